// Round 8
// baseline (1148.564 us; speedup 1.0000x reference)
//
#include <hip/hip_runtime.h>
#include <hip/hip_bf16.h>
#include <math.h>

#define NB 64
#define NS 1024
#define NH 1024
#define NE 1024
#define NA 1024

// scores geometry: block = 128 s x 256 a, BK=32, 8 waves (2s x 4a), wave-out 64x64
#define A_TILE 8192        // 128 rows x 32 bf16 x 2B
#define B_TILE 16384       // 256 rows x 32 bf16 x 2B
#define BUF_BYTES 49152    // [aHi 8K][aLo 8K][bHi 16K][bLo 16K]
#define NT 128             // 4 a-chunks x 32 e-tiles

typedef __attribute__((ext_vector_type(8))) short bf16x8;
typedef __attribute__((ext_vector_type(8))) unsigned short ushort8_t;
typedef __attribute__((ext_vector_type(4))) float f32x4;

__device__ __forceinline__ unsigned short f2bf(float x) {
    __hip_bfloat16 h = __float2bfloat16(x);
    return *reinterpret_cast<unsigned short*>(&h);
}
__device__ __forceinline__ float bf2f(unsigned short u) {
    __hip_bfloat16 h = *reinterpret_cast<__hip_bfloat16*>(&u);
    return __bfloat162float(h);
}
__device__ __forceinline__ float tanh_fast(float x) {
    float ax = fabsf(x);
    float e = __expf(-2.f * ax);
    float r = (1.f - e) / (1.f + e);
    return x < 0.f ? -r : r;
}
// 64-B rows (32 bf16): XOR 16B-slot bits [5:4] with (row>>1)&3. Conflict-free (R6: SQ_LDS_BANK_CONFLICT=0).
__device__ __forceinline__ int swz32(int row, int bcol) {
    return row * 64 + (bcol ^ (((row >> 1) & 3) << 4));
}
__device__ __forceinline__ void gload_lds16(const void* g, void* l) {
    __builtin_amdgcn_global_load_lds(
        (const __attribute__((address_space(1))) unsigned int*)g,
        (__attribute__((address_space(3))) unsigned int*)l, 16, 0, 0);
}

// ---- split enc -> pre-swizzled 128x32 bf16 hi/lo tiles; wave writes contiguous 1KB runs ----
__global__ __launch_bounds__(256) void split_enc_kernel(
    const float* __restrict__ enc,
    unsigned short* __restrict__ encHiT, unsigned short* __restrict__ encLoT)
{
    const int sblk = blockIdx.x;   // 0..7
    const int b    = blockIdx.y;   // 0..63
    const int t    = threadIdx.x;  // 0..255
    const float* src = enc + ((size_t)b * NS + sblk * 128) * NE;
    char* hiB = (char*)encHiT + (size_t)(b * 8 + sblk) * 32 * A_TILE;
    char* loB = (char*)encLoT + (size_t)(b * 8 + sblk) * 32 * A_TILE;
    for (int et = 0; et < 32; ++et) {
#pragma unroll
        for (int i = 0; i < 2; ++i) {
            const int flat = i * 256 + t;       // 0..511
            const int row  = flat >> 2;         // 0..127
            const int c16  = (flat & 3) * 16;   // byte col within 64B row: 0,16,32,48
            const int ecol = et * 32 + c16 / 2; // first of 8 source floats
            const float4 v0 = *reinterpret_cast<const float4*>(src + (size_t)row * NE + ecol);
            const float4 v1 = *reinterpret_cast<const float4*>(src + (size_t)row * NE + ecol + 4);
            ushort8_t h, l;
            h[0] = f2bf(v0.x); l[0] = f2bf(v0.x - bf2f(h[0]));
            h[1] = f2bf(v0.y); l[1] = f2bf(v0.y - bf2f(h[1]));
            h[2] = f2bf(v0.z); l[2] = f2bf(v0.z - bf2f(h[2]));
            h[3] = f2bf(v0.w); l[3] = f2bf(v0.w - bf2f(h[3]));
            h[4] = f2bf(v1.x); l[4] = f2bf(v1.x - bf2f(h[4]));
            h[5] = f2bf(v1.y); l[5] = f2bf(v1.y - bf2f(h[5]));
            h[6] = f2bf(v1.z); l[6] = f2bf(v1.z - bf2f(h[6]));
            h[7] = f2bf(v1.w); l[7] = f2bf(v1.w - bf2f(h[7]));
            const int off = et * A_TILE + swz32(row, c16);
            *reinterpret_cast<int4*>(hiB + off) = *reinterpret_cast<int4*>(&h);
            *reinterpret_cast<int4*>(loB + off) = *reinterpret_cast<int4*>(&l);
        }
    }
}

// ---- split Ua^T -> pre-swizzled 256x32 bf16 hi/lo tiles, (ac) x 32 et ----
__global__ __launch_bounds__(256) void split_uat_kernel(
    const float* __restrict__ Ua,
    unsigned short* __restrict__ uatHiT, unsigned short* __restrict__ uatLoT)
{
    __shared__ float ls[32][257];
    const int ac = blockIdx.x;     // 0..3   (a-chunk of 256)
    const int eb = blockIdx.y;     // 0..31  (== et)
    const int t  = threadIdx.x;
    const int a0 = ac * 256, e0 = eb * 32;
#pragma unroll
    for (int p = 0; p < 8; ++p) {
        const int flat = p * 256 + t;      // 2048 float4: e(32) x q(64)
        const int e = flat >> 6, q = flat & 63;
        *reinterpret_cast<float4*>(&ls[e][q * 4]) =
            *reinterpret_cast<const float4*>(Ua + (size_t)(e0 + e) * NA + a0 + q * 4);
    }
    __syncthreads();
    char* hiT = (char*)uatHiT + (size_t)(ac * 32 + eb) * B_TILE;
    char* loT = (char*)uatLoT + (size_t)(ac * 32 + eb) * B_TILE;
#pragma unroll
    for (int p = 0; p < 4; ++p) {
        const int flat = p * 256 + t;      // 1024: a(256) x octet(4)
        const int a = flat >> 2, o = flat & 3;
        ushort8_t h8, l8;
#pragma unroll
        for (int j = 0; j < 8; ++j) {
            const float x = ls[o * 8 + j][a];
            const unsigned short hh = f2bf(x);
            h8[j] = hh;
            l8[j] = f2bf(x - bf2f(hh));
        }
        const int off = swz32(a, o * 16);
        *reinterpret_cast<int4*>(hiT + off) = *reinterpret_cast<int4*>(&h8);
        *reinterpret_cast<int4*>(loT + off) = *reinterpret_cast<int4*>(&l8);
    }
}

// ---- k_dec = dec @ W_a ----
__global__ __launch_bounds__(256) void kdec_kernel(
    const float* __restrict__ dec, const float* __restrict__ Wa,
    float* __restrict__ kdec)
{
    __shared__ float dls[NH];
    const int b = blockIdx.x;
    const int a = blockIdx.y * 256 + threadIdx.x;
    for (int i = threadIdx.x; i < NH; i += 256) dls[i] = dec[b * NH + i];
    __syncthreads();
    float acc = 0.f;
#pragma unroll 8
    for (int h = 0; h < NH; ++h) acc += dls[h] * Wa[(size_t)h * NA + a];
    kdec[b * NA + a] = acc;
}

// ---- fused scores: split-bf16 MFMA, 4-phase-per-K-tile schedule (m201-style T3+T4+T5) ----
__global__ __launch_bounds__(512, 2) void scores_mfma3_kernel(
    const unsigned short* __restrict__ encHiT, const unsigned short* __restrict__ encLoT,
    const unsigned short* __restrict__ uatHiT, const unsigned short* __restrict__ uatLoT,
    const float* __restrict__ kdec, const float* __restrict__ va,
    float* __restrict__ scores)
{
    __shared__ __align__(16) char lds[3 * BUF_BYTES];   // 147456 B
    __shared__ float scLds[4][128];

    const int t    = threadIdx.x;
    const int sblk = blockIdx.x;
    const int b    = blockIdx.y;
    const int lane = t & 63;
    const int wid  = t >> 6;        // 0..7
    const int wr   = wid >> 2;      // 0..1 (64 s-rows)
    const int wc   = wid & 3;       // 0..3 (64 a-cols)
    const int lrow = lane & 15;
    const int kb   = (lane >> 4) * 16;   // byte col of k-octet

    const char* aHiB = (const char*)encHiT + (size_t)(b * 8 + sblk) * 32 * A_TILE;
    const char* aLoB = (const char*)encLoT + (size_t)(b * 8 + sblk) * 32 * A_TILE;
    const char* bHiB = (const char*)uatHiT;
    const char* bLoB = (const char*)uatLoT;

    // swizzle-invariant LDS read offsets
    int aOff[4], bOff[4];
#pragma unroll
    for (int f = 0; f < 4; ++f) {
        aOff[f] = swz32(wr * 64 + f * 16 + lrow, kb);
        bOff[f] = swz32(wc * 64 + f * 16 + lrow, kb);
    }

    // preload kdec/va; then drain vmcnt so these loads never pollute the counted protocol
    float kd[4][4], vv[4][4];
#pragma unroll
    for (int ac = 0; ac < 4; ++ac)
#pragma unroll
        for (int fj = 0; fj < 4; ++fj) {
            const int a = ac * 256 + wc * 64 + fj * 16 + lrow;
            kd[ac][fj] = kdec[(size_t)b * NA + a];
            vv[ac][fj] = va[a];
        }
    asm volatile("s_waitcnt vmcnt(0)" ::: "memory");

    auto STAGE_HALF = [&](int g, int buf, int half) {
        const int ac2 = g >> 5, et2 = g & 31;
        const char* aHi = aHiB + (size_t)et2 * A_TILE;
        const char* aLo = aLoB + (size_t)et2 * A_TILE;
        const char* bHi = bHiB + (size_t)(ac2 * 32 + et2) * B_TILE;
        const char* bLo = bLoB + (size_t)(ac2 * 32 + et2) * B_TILE;
        char* dst = lds + buf * BUF_BYTES;
        const int so = t * 16;          // per-lane source offset
        const int wo = wid * 1024;      // wave-uniform LDS base
        if (half == 0) {
            gload_lds16(aHi + so,        dst + 0 * 8192 + wo);
            gload_lds16(aLo + so,        dst + 1 * 8192 + wo);
            gload_lds16(bHi + so,        dst + 2 * 8192 + wo);
        } else {
            gload_lds16(bHi + 8192 + so, dst + 3 * 8192 + wo);
            gload_lds16(bLo + so,        dst + 4 * 8192 + wo);
            gload_lds16(bLo + 8192 + so, dst + 5 * 8192 + wo);
        }
    };

    float scp[4][4];
#pragma unroll
    for (int i = 0; i < 4; ++i)
#pragma unroll
        for (int r = 0; r < 4; ++r) scp[i][r] = 0.f;

    // prologue: stage tiles 0,1; wait tile 0 (6 of tile 1 remain in flight)
    STAGE_HALF(0, 0, 0); STAGE_HALF(0, 0, 1);
    STAGE_HALF(1, 1, 0); STAGE_HALF(1, 1, 1);
    asm volatile("s_waitcnt vmcnt(6)" ::: "memory");
    asm volatile("s_barrier" ::: "memory");

    int cur = 0;
#pragma unroll
    for (int ac = 0; ac < 4; ++ac) {
        f32x4 acc[4][4];
#pragma unroll
        for (int fi = 0; fi < 4; ++fi)
#pragma unroll
            for (int fj = 0; fj < 4; ++fj) acc[fi][fj] = (f32x4){0.f, 0.f, 0.f, 0.f};

        for (int et = 0; et < 32; ++et) {
            const int g = ac * 32 + et;
            const char* L = lds + cur * BUF_BYTES;
            const bool st = (g + 2 < NT);
            int nb = cur + 2; if (nb >= 3) nb -= 3;

            // ===== phase 0: all a-frags + b[0]; MFMA fj=0 =====
            bf16x8 aH[4], aL[4];
#pragma unroll
            for (int f = 0; f < 4; ++f) {
                aH[f] = *reinterpret_cast<const bf16x8*>(L + aOff[f]);
                aL[f] = *reinterpret_cast<const bf16x8*>(L + A_TILE + aOff[f]);
            }
            {
                bf16x8 bh = *reinterpret_cast<const bf16x8*>(L + 2 * A_TILE + bOff[0]);
                bf16x8 bl = *reinterpret_cast<const bf16x8*>(L + 2 * A_TILE + B_TILE + bOff[0]);
                asm volatile("s_barrier" ::: "memory");
                asm volatile("s_waitcnt lgkmcnt(0)" ::: "memory");
                __builtin_amdgcn_sched_barrier(0);
                __builtin_amdgcn_s_setprio(1);
#pragma unroll
                for (int fi = 0; fi < 4; ++fi) {
                    acc[fi][0] = __builtin_amdgcn_mfma_f32_16x16x32_bf16(aH[fi], bh, acc[fi][0], 0, 0, 0);
                    acc[fi][0] = __builtin_amdgcn_mfma_f32_16x16x32_bf16(aH[fi], bl, acc[fi][0], 0, 0, 0);
                    acc[fi][0] = __builtin_amdgcn_mfma_f32_16x16x32_bf16(aL[fi], bh, acc[fi][0], 0, 0, 0);
                }
                __builtin_amdgcn_s_setprio(0);
                __builtin_amdgcn_sched_barrier(0);
                asm volatile("s_barrier" ::: "memory");
            }
            // ===== phase 1: b[1]; stage half 0 of tile g+2; MFMA fj=1 =====
            {
                bf16x8 bh = *reinterpret_cast<const bf16x8*>(L + 2 * A_TILE + bOff[1]);
                bf16x8 bl = *reinterpret_cast<const bf16x8*>(L + 2 * A_TILE + B_TILE + bOff[1]);
                if (st) STAGE_HALF(g + 2, nb, 0);
                asm volatile("s_barrier" ::: "memory");
                asm volatile("s_waitcnt lgkmcnt(0)" ::: "memory");
                __builtin_amdgcn_sched_barrier(0);
                __builtin_amdgcn_s_setprio(1);
#pragma unroll
                for (int fi = 0; fi < 4; ++fi) {
                    acc[fi][1] = __builtin_amdgcn_mfma_f32_16x16x32_bf16(aH[fi], bh, acc[fi][1], 0, 0, 0);
                    acc[fi][1] = __builtin_amdgcn_mfma_f32_16x16x32_bf16(aH[fi], bl, acc[fi][1], 0, 0, 0);
                    acc[fi][1] = __builtin_amdgcn_mfma_f32_16x16x32_bf16(aL[fi], bh, acc[fi][1], 0, 0, 0);
                }
                __builtin_amdgcn_s_setprio(0);
                __builtin_amdgcn_sched_barrier(0);
                asm volatile("s_barrier" ::: "memory");
            }
            // ===== phase 2: b[2]; stage half 1 of tile g+2; MFMA fj=2 =====
            {
                bf16x8 bh = *reinterpret_cast<const bf16x8*>(L + 2 * A_TILE + bOff[2]);
                bf16x8 bl = *reinterpret_cast<const bf16x8*>(L + 2 * A_TILE + B_TILE + bOff[2]);
                if (st) STAGE_HALF(g + 2, nb, 1);
                asm volatile("s_barrier" ::: "memory");
                asm volatile("s_waitcnt lgkmcnt(0)" ::: "memory");
                __builtin_amdgcn_sched_barrier(0);
                __builtin_amdgcn_s_setprio(1);
#pragma unroll
                for (int fi = 0; fi < 4; ++fi) {
                    acc[fi][2] = __builtin_amdgcn_mfma_f32_16x16x32_bf16(aH[fi], bh, acc[fi][2], 0, 0, 0);
                    acc[fi][2] = __builtin_amdgcn_mfma_f32_16x16x32_bf16(aH[fi], bl, acc[fi][2], 0, 0, 0);
                    acc[fi][2] = __builtin_amdgcn_mfma_f32_16x16x32_bf16(aL[fi], bh, acc[fi][2], 0, 0, 0);
                }
                __builtin_amdgcn_s_setprio(0);
                __builtin_amdgcn_sched_barrier(0);
                asm volatile("s_barrier" ::: "memory");
            }
            // ===== phase 3: b[3]; counted vmcnt validates tile g+1; MFMA fj=3 =====
            {
                bf16x8 bh = *reinterpret_cast<const bf16x8*>(L + 2 * A_TILE + bOff[3]);
                bf16x8 bl = *reinterpret_cast<const bf16x8*>(L + 2 * A_TILE + B_TILE + bOff[3]);
                if (st) {
                    asm volatile("s_waitcnt vmcnt(6)" ::: "memory");   // tile g+1 done; g+2 in flight
                } else if (g + 1 < NT) {
                    asm volatile("s_waitcnt vmcnt(0)" ::: "memory");   // last prefetch done
                }
                asm volatile("s_barrier" ::: "memory");
                asm volatile("s_waitcnt lgkmcnt(0)" ::: "memory");
                __builtin_amdgcn_sched_barrier(0);
                __builtin_amdgcn_s_setprio(1);
#pragma unroll
                for (int fi = 0; fi < 4; ++fi) {
                    acc[fi][3] = __builtin_amdgcn_mfma_f32_16x16x32_bf16(aH[fi], bh, acc[fi][3], 0, 0, 0);
                    acc[fi][3] = __builtin_amdgcn_mfma_f32_16x16x32_bf16(aH[fi], bl, acc[fi][3], 0, 0, 0);
                    acc[fi][3] = __builtin_amdgcn_mfma_f32_16x16x32_bf16(aL[fi], bh, acc[fi][3], 0, 0, 0);
                }
                __builtin_amdgcn_s_setprio(0);
                __builtin_amdgcn_sched_barrier(0);
                asm volatile("s_barrier" ::: "memory");   // release buf[cur]
            }
            cur += 1; if (cur >= 3) cur -= 3;
        }

        // epilogue: tanh(kdec + x) * va  (ac literal via unroll -> static indexing)
#pragma unroll
        for (int fj = 0; fj < 4; ++fj)
#pragma unroll
            for (int fi = 0; fi < 4; ++fi)
#pragma unroll
                for (int r = 0; r < 4; ++r)
                    scp[fi][r] += tanh_fast(kd[ac][fj] + acc[fi][fj][r]) * vv[ac][fj];
    }

    // reduce over the 16 col-lanes, then across the 4 a-wave-columns via LDS
#pragma unroll
    for (int fi = 0; fi < 4; ++fi)
#pragma unroll
        for (int r = 0; r < 4; ++r) {
            float v = scp[fi][r];
            v += __shfl_xor(v, 1);
            v += __shfl_xor(v, 2);
            v += __shfl_xor(v, 4);
            v += __shfl_xor(v, 8);
            if (lrow == 0)
                scLds[wc][wr * 64 + fi * 16 + (lane >> 4) * 4 + r] = v;
        }
    __syncthreads();
    if (t < 128)
        scores[(size_t)b * NS + sblk * 128 + t] =
            scLds[0][t] + scLds[1][t] + scLds[2][t] + scLds[3][t];
}

// ---- softmax over S (+ mask), zero ctx region ----
__global__ __launch_bounds__(256) void softmax_kernel(
    const float* __restrict__ scores, const int* __restrict__ mask,
    float* __restrict__ out)
{
    __shared__ float red[8];
    const int b = blockIdx.x;
    const int t = threadIdx.x;
    float v[4];
    float mx = -INFINITY;
#pragma unroll
    for (int i = 0; i < 4; ++i) {
        const int s = t + i * 256;
        float x = scores[b * NS + s];
        if (mask[b * NS + s] == 0) x += -1e9f;
        v[i] = x;
        mx = fmaxf(mx, x);
    }
    for (int off = 1; off < 64; off <<= 1) mx = fmaxf(mx, __shfl_xor(mx, off));
    const int wid = t >> 6;
    if ((t & 63) == 0) red[wid] = mx;
    __syncthreads();
    mx = fmaxf(fmaxf(red[0], red[1]), fmaxf(red[2], red[3]));
    float sum = 0.f;
#pragma unroll
    for (int i = 0; i < 4; ++i) { v[i] = expf(v[i] - mx); sum += v[i]; }
    for (int off = 1; off < 64; off <<= 1) sum += __shfl_xor(sum, off);
    if ((t & 63) == 0) red[4 + wid] = sum;
    __syncthreads();
    sum = red[4] + red[5] + red[6] + red[7];
    const float inv = 1.f / sum;
#pragma unroll
    for (int i = 0; i < 4; ++i) {
        const int s = t + i * 256;
        out[NB * NE + b * NS + s] = v[i] * inv;   // weights
        out[b * NE + s] = 0.f;                     // zero ctx (E==S==1024)
    }
}

// ---- ctx[b,e] = sum_s w[b,s] * enc[b,s,e] ----
__global__ __launch_bounds__(256) void ctx_kernel(
    const float* __restrict__ enc, const float* __restrict__ w,
    float* __restrict__ ctx)
{
    __shared__ float wls[128];
    const int b  = blockIdx.x;
    const int ec = blockIdx.y;
    const int ss = blockIdx.z;
    const int t  = threadIdx.x;
    if (t < 128) wls[t] = w[b * NS + ss * 128 + t];
    __syncthreads();
    const int e = ec * 256 + t;
    const float* p = enc + ((size_t)b * NS + ss * 128) * NE + e;
    float acc = 0.f;
#pragma unroll 4
    for (int s = 0; s < 128; ++s) acc += wls[s] * p[(size_t)s * NE];
    atomicAdd(&ctx[b * NE + e], acc);
}

extern "C" void kernel_launch(void* const* d_in, const int* in_sizes, int n_in,
                              void* d_out, int out_size, void* d_ws, size_t ws_size,
                              hipStream_t stream)
{
    const float* dec  = (const float*)d_in[0];
    const float* enc  = (const float*)d_in[1];
    const int*   mask = (const int*)d_in[2];     // bool -> int32 per harness
    const float* Wa   = (const float*)d_in[3];
    const float* Ua   = (const float*)d_in[4];
    const float* va   = (const float*)d_in[5];
    float* out = (float*)d_out;

    float* kdec   = (float*)d_ws;              // 256 KB
    float* scores = kdec + NB * NA;            // 256 KB
    unsigned short* uatHiT = (unsigned short*)(scores + NB * NS);   // 2 MB
    unsigned short* uatLoT = uatHiT + (size_t)NA * NE;              // 2 MB
    unsigned short* encHiT = uatLoT + (size_t)NA * NE;              // 128 MB
    unsigned short* encLoT = encHiT + (size_t)NB * NS * NE;         // 128 MB

    kdec_kernel<<<dim3(NB, NA / 256), 256, 0, stream>>>(dec, Wa, kdec);
    split_uat_kernel<<<dim3(4, 32), 256, 0, stream>>>(Ua, uatHiT, uatLoT);
    split_enc_kernel<<<dim3(8, NB), 256, 0, stream>>>(enc, encHiT, encLoT);
    scores_mfma3_kernel<<<dim3(8, NB), 512, 0, stream>>>(
        encHiT, encLoT, uatHiT, uatLoT, kdec, va, scores);
    softmax_kernel<<<dim3(NB), 256, 0, stream>>>(scores, mask, out);
    ctx_kernel<<<dim3(NB, NE / 256, NS / 128), 256, 0, stream>>>(enc, out + NB * NE, out);
}